// Round 8
// baseline (13365.845 us; speedup 1.0000x reference)
//
#include <hip/hip_runtime.h>
#include <hip/hip_bf16.h>

#define T_ 256
#define B_ 128
#define H_ 512
#define G3 1536
#define SCH 32      // timesteps per chunk
#define NCH 8       // chunks per layer
#define RWG 32      // rec WGs (8 unit-groups x 4 batch-groups); each WG does BOTH dirs
#define BGRP 8      // WGs per barrier group (same bg, all ug)

typedef __attribute__((ext_vector_type(8))) short short8;
typedef __attribute__((ext_vector_type(4))) short short4v;
typedef __attribute__((ext_vector_type(4))) float f32x4;

static __device__ __forceinline__ float b2f(short s){
    unsigned u = ((unsigned)(unsigned short)s) << 16;
    return __builtin_bit_cast(float, u);
}
static __device__ __forceinline__ short f2b(float f){
    __hip_bfloat16 h = __float2bfloat16(f);   // RNE
    return __builtin_bit_cast(short, h);
}
static __device__ __forceinline__ void gload16(const void* g, void* l){
    __builtin_amdgcn_global_load_lds(
        (__attribute__((address_space(1))) void*)(void*)g,
        (__attribute__((address_space(3))) void*)l, 16, 0, 0);
}
// coherent (device-scope) 16B load: bypasses stale L1/L2 (sc0 sc1)
static __device__ __forceinline__ short8 gload_sc(const short* p){
    short8 v;
    asm volatile("global_load_dwordx4 %0, %1, off sc0 sc1"
                 : "=v"(v) : "v"(p) : "memory");
    return v;
}
// coherent write-through 2B store
static __device__ __forceinline__ void gstore_sc(short* p, short v){
    asm volatile("global_store_short %0, %1, off sc0 sc1"
                 :: "v"(p), "v"(v) : "memory");
}
static __device__ __forceinline__ void wait_vm0(){
    asm volatile("s_waitcnt vmcnt(0)" ::: "memory");
}

// ---------------- fp32 -> bf16 conversion ----------------
__global__ void cvt_f32_to_bf16(const float* __restrict__ src, short* __restrict__ dst, int n){
    int i = (blockIdx.x * blockDim.x + threadIdx.x) * 4;
    int stride = gridDim.x * blockDim.x * 4;
    for (; i + 3 < n; i += stride){
        float4 v = *(const float4*)(src + i);
        short4v o;
        o[0] = f2b(v.x); o[1] = f2b(v.y); o[2] = f2b(v.z); o[3] = f2b(v.w);
        *(short4v*)(dst + i) = o;
    }
}

// ---------------- gx chunk GEMM (m97-style 128x128 tile, bf16 out) ----------------
__global__ __launch_bounds__(256) void gx_gemm(
    const short* __restrict__ A,     // [T*B][K] bf16
    const short* __restrict__ W,     // [2*1536][K] bf16
    const float* __restrict__ bias,  // [2*1536] fp32
    short* __restrict__ gxc,         // [2][SCH*128][1536] bf16
    int K, int t0f, int t0b_lo)
{
    __shared__ __align__(16) short sA[4096];   // [128][32]
    __shared__ __align__(16) short sB[4096];
    const int dir = blockIdx.z;
    const int t0 = dir ? t0b_lo : t0f;
    const int m0 = blockIdx.x * 128;
    const int n0 = blockIdx.y * 128;
    const short* Ae = A + (size_t)(t0 * B_) * K;
    const short* We = W + (size_t)dir * G3 * K;
    short* out = gxc + (size_t)dir * ((size_t)SCH * B_ * G3);

    const int tid = threadIdx.x, wv = tid >> 6, lane = tid & 63;
    const int moff = (wv & 1) * 64, noff = (wv >> 1) * 64;
    const int e0 = wv * 1024 + lane * 8, e1 = e0 + 512;
    const short* a0 = Ae + (size_t)(m0 + (e0 >> 5)) * K + (e0 & 31);
    const short* a1 = Ae + (size_t)(m0 + (e1 >> 5)) * K + (e1 & 31);
    const short* b0 = We + (size_t)(n0 + (e0 >> 5)) * K + (e0 & 31);
    const short* b1 = We + (size_t)(n0 + (e1 >> 5)) * K + (e1 & 31);
    short* sa0 = &sA[wv * 1024];  short* sa1 = &sA[wv * 1024 + 512];
    short* sb0 = &sB[wv * 1024];  short* sb1 = &sB[wv * 1024 + 512];

    f32x4 acc[4][4] = {};
    const int lr = lane & 15, lk = (lane >> 4) * 8;

    for (int kk = 0; kk < K; kk += 32){
        gload16(a0 + kk, sa0); gload16(a1 + kk, sa1);
        gload16(b0 + kk, sb0); gload16(b1 + kk, sb1);
        __syncthreads();
        short8 ar[4], br[4];
        #pragma unroll
        for (int i = 0; i < 4; ++i) ar[i] = *(const short8*)&sA[(moff + i*16 + lr) * 32 + lk];
        #pragma unroll
        for (int i = 0; i < 4; ++i) br[i] = *(const short8*)&sB[(noff + i*16 + lr) * 32 + lk];
        #pragma unroll
        for (int ai = 0; ai < 4; ++ai)
            #pragma unroll
            for (int bi = 0; bi < 4; ++bi)
                acc[ai][bi] = __builtin_amdgcn_mfma_f32_16x16x32_bf16(ar[ai], br[bi], acc[ai][bi], 0, 0, 0);
        __syncthreads();
    }

    #pragma unroll
    for (int ai = 0; ai < 4; ++ai){
        #pragma unroll
        for (int bi = 0; bi < 4; ++bi){
            int col = n0 + noff + bi*16 + lr;
            float bv = bias[dir * G3 + col];
            #pragma unroll
            for (int r = 0; r < 4; ++r){
                int row = m0 + moff + ai*16 + ((lane >> 4) << 2) + r;
                out[(size_t)row * G3 + col] = f2b(acc[ai][bi][r] + bv);
            }
        }
    }
}

// ---------------- persistent chunk recurrence, direction-interleaved ----------------
// grid (32): blockIdx.x = ug*4+bg. block 256 (4 waves). Each WG runs BOTH directions'
// chains for its (64 units x 32 rows) slice, alternating f/b phases so each chain's
// sync latency (sc-store drain + atomic + spin + sc-load) hides behind the other
// chain's compute. Whh for both dirs register-resident (384 regs, unified VGPR/AGPR).
// gx gate-inputs staged via async global_load_lds, double-buffered, prefetched 1 step.
__global__ __launch_bounds__(256, 1) void rec_kernel(
    const short* __restrict__ gxc,   // [2][SCH*128][1536] bf16 (b_ih folded)
    const short* __restrict__ Whh,   // [2*1536][512] bf16
    const float* __restrict__ bhh,   // [2*1536] fp32
    short* __restrict__ xout,        // [T][B][1024] bf16
    float* __restrict__ hfm,         // [2][128][512] fp32 master (cross-launch)
    short* __restrict__ hbb,         // [2 parity][2 dir][128][512] bf16
    int* __restrict__ bar,           // per (bg,dir): monotonic counter, stride 32 ints
    int t0f, int t0b_hi, int first, int base)
{
    __shared__ __align__(16) short lds_h[32 * 520];        // shared by f/b phases
    __shared__ __align__(16) short lds_gx[2][2][3 * 2048]; // [dir][parity][g*2048 + lrow*64 + unit]
    const int tid = threadIdx.x, wv = tid >> 6, lane = tid & 63;
    const int ug = blockIdx.x >> 2, bg = blockIdx.x & 3;
    const int u0w = ug * 64;
    const int u0 = u0w + wv * 16;
    const int m0 = bg * 32;
    const int lr = lane & 15, lk = (lane >> 4) * 8;
    const int crow = (lane >> 4) * 4;
    const int srow = tid >> 3, scol0 = (tid & 7) * 8;   // staging role
    const int uw = wv * 16 + lr;                        // unit index within WG slice

    // ---- resident weight fragments, BOTH dirs: 2 x 3 gates x 16 k = 384 regs
    short8 wreg[2][3][16];
    #pragma unroll
    for (int d = 0; d < 2; ++d)
        #pragma unroll
        for (int g = 0; g < 3; ++g)
            #pragma unroll
            for (int kk = 0; kk < 16; ++kk)
                wreg[d][g][kk] = *(const short8*)&Whh[
                    ((size_t)(d*G3 + g*H_ + u0 + lr)) * H_ + kk*32 + lk];

    float bh[2][3];
    #pragma unroll
    for (int d = 0; d < 2; ++d)
        #pragma unroll
        for (int g = 0; g < 3; ++g)
            bh[d][g] = bhh[d*G3 + g*H_ + u0 + lr];

    float hreg[2][2][4];
    #pragma unroll
    for (int d = 0; d < 2; ++d)
        #pragma unroll
        for (int mt = 0; mt < 2; ++mt)
            #pragma unroll
            for (int r = 0; r < 4; ++r)
                hreg[d][mt][r] = first ? 0.f
                    : hfm[((size_t)d*B_ + m0 + mt*16 + crow + r)*H_ + u0 + lr];

    // ---- prologue: stage gx(sl=0) for both dirs into parity 0 (async)
    #pragma unroll
    for (int d = 0; d < 2; ++d){
        const int tl0 = d ? (SCH - 1) : 0;
        const short* gsrc = gxc + (size_t)d * ((size_t)SCH * B_ * G3)
                          + ((size_t)(tl0 * B_) + m0 + srow) * G3 + u0w + scol0;
        #pragma unroll
        for (int g = 0; g < 3; ++g)
            gload16(gsrc + g * H_, &lds_gx[d][0][g * 2048 + tid * 8]);
    }

    for (int sl = 0; sl < SCH; ++sl){
        const int rp = sl & 1;
        #pragma unroll
        for (int d = 0; d < 2; ++d){
            const int t  = d ? (t0b_hi - sl) : (t0f + sl);
            int* cnt = bar + (bg*2 + d) * 32;

            // ---- wait: this dir's step-(sl-1) h complete (instant in steady state)
            if (tid == 0){
                const int tgt = (base + sl) * BGRP;
                while (__hip_atomic_load(cnt, __ATOMIC_RELAXED, __HIP_MEMORY_SCOPE_AGENT) < tgt)
                    __builtin_amdgcn_s_sleep(1);
            }
            __syncthreads();

            // ---- stage h[rp][d] tile into LDS (coherent loads), prefetch next gx
            {
                const short* hsrc = hbb + ((size_t)(rp*2 + d) * B_ + m0) * H_;
                short8 hv[8];
                #pragma unroll
                for (int c = 0; c < 8; ++c)
                    hv[c] = gload_sc(hsrc + (size_t)srow * H_ + scol0 + c*64);
                if (sl + 1 < SCH){
                    const int tln = d ? (SCH - 2 - sl) : (sl + 1);
                    const short* gsrc = gxc + (size_t)d * ((size_t)SCH * B_ * G3)
                                      + ((size_t)(tln * B_) + m0 + srow) * G3 + u0w + scol0;
                    #pragma unroll
                    for (int g = 0; g < 3; ++g)
                        gload16(gsrc + g * H_, &lds_gx[d][rp ^ 1][g * 2048 + tid * 8]);
                }
                wait_vm0();
                #pragma unroll
                for (int c = 0; c < 8; ++c)
                    *(short8*)&lds_h[srow * 520 + scol0 + c*64] = hv[c];
            }
            __syncthreads();

            // ---- recurrent GEMM from LDS, B resident
            f32x4 acc[3][2] = {};
            #pragma unroll
            for (int kk = 0; kk < 16; ++kk){
                short8 a0 = *(const short8*)&lds_h[(lr)      * 520 + kk*32 + lk];
                short8 a1 = *(const short8*)&lds_h[(16 + lr) * 520 + kk*32 + lk];
                #pragma unroll
                for (int g = 0; g < 3; ++g){
                    acc[g][0] = __builtin_amdgcn_mfma_f32_16x16x32_bf16(a0, wreg[d][g][kk], acc[g][0], 0, 0, 0);
                    acc[g][1] = __builtin_amdgcn_mfma_f32_16x16x32_bf16(a1, wreg[d][g][kk], acc[g][1], 0, 0, 0);
                }
            }

            // ---- gates + h update; coherent h store, plain xout store
            short* hwr = hbb + ((size_t)((rp^1)*2 + d) * B_) * H_;
            #pragma unroll
            for (int mt = 0; mt < 2; ++mt){
                #pragma unroll
                for (int r = 0; r < 4; ++r){
                    const int lrow = mt*16 + crow + r;      // chunk-local row = row - m0
                    const int row  = m0 + lrow;
                    float xr = b2f(lds_gx[d][rp][0*2048 + lrow * 64 + uw]);
                    float xz = b2f(lds_gx[d][rp][1*2048 + lrow * 64 + uw]);
                    float xn = b2f(lds_gx[d][rp][2*2048 + lrow * 64 + uw]);
                    float gr = acc[0][mt][r] + bh[d][0] + xr;
                    float gz = acc[1][mt][r] + bh[d][1] + xz;
                    float gn = acc[2][mt][r] + bh[d][2];
                    float rg = 1.f / (1.f + __expf(-gr));
                    float zg = 1.f / (1.f + __expf(-gz));
                    float e2 = __expf(2.f * (xn + rg * gn));
                    float ng = 1.f - 2.f / (e2 + 1.f);            // tanh, inf-safe
                    float hn = (1.f - zg) * ng + zg * hreg[d][mt][r];
                    hreg[d][mt][r] = hn;
                    short h16 = f2b(hn);
                    gstore_sc(hwr + (size_t)row * H_ + u0 + lr, h16);
                    xout[((size_t)t * B_ + row) * 1024 + d*H_ + u0 + lr] = h16;
                }
            }

            // ---- arrive: drain sc-stores (all waves), then count
            wait_vm0();
            __syncthreads();
            if (tid == 0)
                __hip_atomic_fetch_add(cnt, 1, __ATOMIC_RELAXED, __HIP_MEMORY_SCOPE_AGENT);
        }
    }

    // persist fp32 master across chunk launches
    #pragma unroll
    for (int d = 0; d < 2; ++d)
        #pragma unroll
        for (int mt = 0; mt < 2; ++mt)
            #pragma unroll
            for (int r = 0; r < 4; ++r)
                hfm[((size_t)d*B_ + m0 + mt*16 + crow + r)*H_ + u0 + lr] = hreg[d][mt][r];
}

// ---------------- final FC + sigmoid ----------------
__global__ void fc_kernel(const short* __restrict__ h, const float* __restrict__ w,
                          const float* __restrict__ b, float* __restrict__ out){
    int wid = threadIdx.x >> 6, lane = threadIdx.x & 63;
    int tb = blockIdx.x * 4 + wid;
    const short* hp = h + (size_t)tb * 1024 + lane * 16;
    float s = 0.f;
    #pragma unroll
    for (int c = 0; c < 2; ++c){
        short8 v = *(const short8*)(hp + c * 8);
        #pragma unroll
        for (int e = 0; e < 8; ++e) s += b2f(v[e]) * w[lane * 16 + c * 8 + e];
    }
    #pragma unroll
    for (int o = 32; o; o >>= 1) s += __shfl_down(s, o);
    if (lane == 0) out[tb] = 1.f / (1.f + __expf(-(s + b[0])));
}

extern "C" void kernel_launch(void* const* d_in, const int* in_sizes, int n_in,
                              void* d_out, int out_size, void* d_ws, size_t ws_size,
                              hipStream_t stream){
    const float* input_seq = (const float*)d_in[0];
    const float* W_ih0 = (const float*)d_in[1];
    const float* W_hh0 = (const float*)d_in[2];
    const float* b_ih0 = (const float*)d_in[3];
    const float* b_hh0 = (const float*)d_in[4];
    const float* W_ih  = (const float*)d_in[5];
    const float* W_hh  = (const float*)d_in[6];
    const float* b_ih  = (const float*)d_in[7];
    const float* b_hh  = (const float*)d_in[8];
    const float* fc_w  = (const float*)d_in[9];
    const float* fc_b  = (const float*)d_in[10];
    (void)in_sizes; (void)n_in; (void)out_size; (void)ws_size;

    char* ws = (char*)d_ws;
    size_t off = 0;
    auto alloc = [&](size_t bytes) -> char* {
        char* p = ws + off; off += (bytes + 255) & ~(size_t)255; return p;
    };
    short* actA = (short*)alloc((size_t)T_*B_*1024 * 2);          // 67.1 MB
    short* actB = (short*)alloc((size_t)T_*B_*1024 * 2);          // 67.1 MB
    short* gxc  = (short*)alloc((size_t)2*SCH*B_*G3 * 2);         // 25.2 MB
    short* wihl = (short*)alloc((size_t)2*G3*1024 * 2);           // 6.3 MB
    short* whhl = (short*)alloc((size_t)2*G3*H_ * 2);             // 3.1 MB
    float* hfm  = (float*)alloc((size_t)2*B_*H_ * 4);             // 0.5 MB
    short* hbb  = (short*)alloc((size_t)2*2*B_*H_ * 2);           // 0.5 MB
    int*   bar  = (int*)alloc(4096);

    auto cvt = [&](const float* s, short* d, size_t n){
        int blocks = (int)((n/4 + 255) / 256); if (blocks > 4096) blocks = 4096;
        hipLaunchKernelGGL(cvt_f32_to_bf16, dim3(blocks), dim3(256), 0, stream, s, d, (int)n);
    };

    // layer-0 input as [T*B][128] bf16 in actB's head
    cvt(input_seq, actB, (size_t)T_*B_*128);

    for (int l = 0; l < 5; ++l){
        const int K = l ? 1024 : 128;
        cvt(l ? W_ih + (size_t)(l-1)*2*G3*1024 : W_ih0, wihl, (size_t)2*G3*K);
        cvt(l ? W_hh + (size_t)(l-1)*2*G3*H_   : W_hh0, whhl, (size_t)2*G3*H_);
        const short* IN  = (l & 1) ? actA : actB;
        short*       OUT = (l & 1) ? actB : actA;
        const float* bi = l ? b_ih + (size_t)(l-1)*2*G3 : b_ih0;
        const float* bh = l ? b_hh + (size_t)(l-1)*2*G3 : b_hh0;

        hipMemsetAsync(hbb, 0, (size_t)2*2*B_*H_*2, stream);   // h(t=0)=0, both parities
        hipMemsetAsync(bar, 0, 4096, stream);                  // arrival counters

        for (int q = 0; q < NCH; ++q){
            const int t0f    = SCH * q;
            const int t0b_hi = T_ - 1 - SCH * q;
            const int t0b_lo = t0b_hi - SCH + 1;
            hipLaunchKernelGGL(gx_gemm, dim3(SCH*B_/128, G3/128, 2), dim3(256), 0, stream,
                               IN, wihl, bi, gxc, K, t0f, t0b_lo);
            hipLaunchKernelGGL(rec_kernel, dim3(RWG), dim3(256), 0, stream,
                               gxc, whhl, bh, OUT, hfm, hbb, bar, t0f, t0b_hi, q == 0, q*SCH);
        }
    }
    // layer 4 wrote actA
    hipLaunchKernelGGL(fc_kernel, dim3((T_*B_)/4), dim3(256), 0, stream,
                       actA, fc_w, fc_b, (float*)d_out);
}

// Round 9
// 9103.606 us; speedup vs baseline: 1.4682x; 1.4682x over previous
//
#include <hip/hip_runtime.h>
#include <hip/hip_bf16.h>

#define T_ 256
#define B_ 128
#define H_ 512
#define G3 1536
#define SCH 32      // timesteps per chunk
#define NCH 8       // chunks per layer
#define RWG 32      // rec WGs per dir (8 unit-groups x 4 batch-groups)
#define BGRP 8      // producers per barrier group (same dir,bg,half; all ug)

typedef __attribute__((ext_vector_type(8))) short short8;
typedef __attribute__((ext_vector_type(4))) short short4v;
typedef __attribute__((ext_vector_type(4))) float f32x4;

static __device__ __forceinline__ float b2f(short s){
    unsigned u = ((unsigned)(unsigned short)s) << 16;
    return __builtin_bit_cast(float, u);
}
static __device__ __forceinline__ short f2b(float f){
    __hip_bfloat16 h = __float2bfloat16(f);   // RNE
    return __builtin_bit_cast(short, h);
}
static __device__ __forceinline__ void gload16(const void* g, void* l){
    __builtin_amdgcn_global_load_lds(
        (__attribute__((address_space(1))) void*)(void*)g,
        (__attribute__((address_space(3))) void*)l, 16, 0, 0);
}
// coherent (device-scope) 16B load: bypasses stale L1/L2 (sc0 sc1)
static __device__ __forceinline__ short8 gload_sc(const short* p){
    short8 v;
    asm volatile("global_load_dwordx4 %0, %1, off sc0 sc1"
                 : "=v"(v) : "v"(p) : "memory");
    return v;
}
// coherent write-through 2B store
static __device__ __forceinline__ void gstore_sc(short* p, short v){
    asm volatile("global_store_short %0, %1, off sc0 sc1"
                 :: "v"(p), "v"(v) : "memory");
}
static __device__ __forceinline__ void wait_vm0(){
    asm volatile("s_waitcnt vmcnt(0)" ::: "memory");
}

// ---------------- fp32 -> bf16 conversion ----------------
__global__ void cvt_f32_to_bf16(const float* __restrict__ src, short* __restrict__ dst, int n){
    int i = (blockIdx.x * blockDim.x + threadIdx.x) * 4;
    int stride = gridDim.x * blockDim.x * 4;
    for (; i + 3 < n; i += stride){
        float4 v = *(const float4*)(src + i);
        short4v o;
        o[0] = f2b(v.x); o[1] = f2b(v.y); o[2] = f2b(v.z); o[3] = f2b(v.w);
        *(short4v*)(dst + i) = o;
    }
}

// ---------------- gx chunk GEMM (m97-style 128x128 tile, bf16 out) ----------------
__global__ __launch_bounds__(256) void gx_gemm(
    const short* __restrict__ A,     // [T*B][K] bf16
    const short* __restrict__ W,     // [2*1536][K] bf16
    const float* __restrict__ bias,  // [2*1536] fp32
    short* __restrict__ gxc,         // [2][SCH*128][1536] bf16
    int K, int t0f, int t0b_lo)
{
    __shared__ __align__(16) short sA[4096];   // [128][32]
    __shared__ __align__(16) short sB[4096];
    const int dir = blockIdx.z;
    const int t0 = dir ? t0b_lo : t0f;
    const int m0 = blockIdx.x * 128;
    const int n0 = blockIdx.y * 128;
    const short* Ae = A + (size_t)(t0 * B_) * K;
    const short* We = W + (size_t)dir * G3 * K;
    short* out = gxc + (size_t)dir * ((size_t)SCH * B_ * G3);

    const int tid = threadIdx.x, wv = tid >> 6, lane = tid & 63;
    const int moff = (wv & 1) * 64, noff = (wv >> 1) * 64;
    const int e0 = wv * 1024 + lane * 8, e1 = e0 + 512;
    const short* a0 = Ae + (size_t)(m0 + (e0 >> 5)) * K + (e0 & 31);
    const short* a1 = Ae + (size_t)(m0 + (e1 >> 5)) * K + (e1 & 31);
    const short* b0 = We + (size_t)(n0 + (e0 >> 5)) * K + (e0 & 31);
    const short* b1 = We + (size_t)(n0 + (e1 >> 5)) * K + (e1 & 31);
    short* sa0 = &sA[wv * 1024];  short* sa1 = &sA[wv * 1024 + 512];
    short* sb0 = &sB[wv * 1024];  short* sb1 = &sB[wv * 1024 + 512];

    f32x4 acc[4][4] = {};
    const int lr = lane & 15, lk = (lane >> 4) * 8;

    for (int kk = 0; kk < K; kk += 32){
        gload16(a0 + kk, sa0); gload16(a1 + kk, sa1);
        gload16(b0 + kk, sb0); gload16(b1 + kk, sb1);
        __syncthreads();
        short8 ar[4], br[4];
        #pragma unroll
        for (int i = 0; i < 4; ++i) ar[i] = *(const short8*)&sA[(moff + i*16 + lr) * 32 + lk];
        #pragma unroll
        for (int i = 0; i < 4; ++i) br[i] = *(const short8*)&sB[(noff + i*16 + lr) * 32 + lk];
        #pragma unroll
        for (int ai = 0; ai < 4; ++ai)
            #pragma unroll
            for (int bi = 0; bi < 4; ++bi)
                acc[ai][bi] = __builtin_amdgcn_mfma_f32_16x16x32_bf16(ar[ai], br[bi], acc[ai][bi], 0, 0, 0);
        __syncthreads();
    }

    #pragma unroll
    for (int ai = 0; ai < 4; ++ai){
        #pragma unroll
        for (int bi = 0; bi < 4; ++bi){
            int col = n0 + noff + bi*16 + lr;
            float bv = bias[dir * G3 + col];
            #pragma unroll
            for (int r = 0; r < 4; ++r){
                int row = m0 + moff + ai*16 + ((lane >> 4) << 2) + r;
                out[(size_t)row * G3 + col] = f2b(acc[ai][bi][r] + bv);
            }
        }
    }
}

// ---------------- persistent chunk recurrence, batch-half pipelined ----------------
// grid (32, 2): blockIdx.x = ug*4+bg, dir = y. block 256 (4 waves).
// Wave wv: units [ug*64+wv*16,+16) x 3 gates; Whh slice resident (192 regs, one dir).
// WG rows split into half A (m0..m0+15) / half B (m0+16..m0+31): independent chains.
// Phase schedule A0,B0,A1,B1,...: each phase issues its h-loads, does ONE combined
// vmcnt(0) draining prev half's h-stores + own loads, posts prev half's arrive, then
// MFMA+gates+store-issue (no drain). Sync latency hides under the other half's phase.
__global__ __launch_bounds__(256, 1) void rec_kernel(
    const short* __restrict__ gxc,   // [2][SCH*128][1536] bf16 (b_ih folded)
    const short* __restrict__ Whh,   // [2*1536][512] bf16
    const float* __restrict__ bhh,   // [2*1536] fp32
    short* __restrict__ xout,        // [T][B][1024] bf16
    float* __restrict__ hfm,         // [2][128][512] fp32 master (cross-launch)
    short* __restrict__ hbb,         // [2 parity][2 dir][128][512] bf16
    int* __restrict__ bar,           // per (dir,bg): halfA cnt, halfB cnt (+16 ints)
    int t0f, int t0b_hi, int first, int base)
{
    __shared__ __align__(16) short lds_h[2][16 * 520];   // per half
    const int tid = threadIdx.x, wv = tid >> 6, lane = tid & 63;
    const int ug = blockIdx.x >> 2, bg = blockIdx.x & 3, dir = blockIdx.y;
    const int u0 = ug * 64 + wv * 16;
    const int m0 = bg * 32;
    const int lr = lane & 15, lk = (lane >> 4) * 8;
    const int crow = (lane >> 4) * 4;
    const int srow = tid >> 4, scol0 = (tid & 15) * 32;  // staging: 16 rows x 1024B

    // ---- resident weight fragments: 3 gates x 16 k-steps = 192 regs (one dir)
    const short* Wd = Whh + (size_t)dir * G3 * H_;
    short8 wreg[3][16];
    #pragma unroll
    for (int g = 0; g < 3; ++g)
        #pragma unroll
        for (int kk = 0; kk < 16; ++kk)
            wreg[g][kk] = *(const short8*)&Wd[(size_t)(g*H_ + u0 + lr) * H_ + kk*32 + lk];

    float bh[3];
    #pragma unroll
    for (int g = 0; g < 3; ++g) bh[g] = bhh[dir*G3 + g*H_ + u0 + lr];

    float hreg[2][4];   // [half][r]
    #pragma unroll
    for (int hf = 0; hf < 2; ++hf)
        #pragma unroll
        for (int r = 0; r < 4; ++r)
            hreg[hf][r] = first ? 0.f
                : hfm[((size_t)dir*B_ + m0 + hf*16 + crow + r)*H_ + u0 + lr];

    int* cntA = bar + (dir*4 + bg) * 32;
    int* cntB = cntA + 16;
    const short* gxd = gxc + (size_t)dir * ((size_t)SCH * B_ * G3);

    for (int ph = 0; ph < 2 * SCH; ++ph){
        const int half = ph & 1, sl = ph >> 1;
        const int rp = sl & 1;
        int* cnt     = half ? cntB : cntA;
        int* cntPrev = half ? cntA : cntB;

        // ---- wait: this half's step-(sl-1) complete across its 8 producers
        if (tid == 0){
            const int tgt = (base + sl) * BGRP;
            while (__hip_atomic_load(cnt, __ATOMIC_RELAXED, __HIP_MEMORY_SCOPE_AGENT) < tgt)
                __builtin_amdgcn_s_sleep(1);
        }
        __syncthreads();

        // ---- issue this half's h loads (coherent) + gx gate-input loads (plain)
        const short* hsrc = hbb + ((size_t)(rp*2 + dir) * B_ + m0 + half*16) * H_;
        short8 hv[4];
        #pragma unroll
        for (int c = 0; c < 4; ++c)
            hv[c] = gload_sc(hsrc + (size_t)srow * H_ + scol0 + c*8);

        const int tl = dir ? (SCH - 1 - sl) : sl;
        const short* gb = gxd + ((size_t)(tl * B_) + m0 + half*16 + crow) * G3 + u0 + lr;
        float gv[3][4];
        #pragma unroll
        for (int g = 0; g < 3; ++g)
            #pragma unroll
            for (int r = 0; r < 4; ++r)
                gv[g][r] = b2f(gb[(size_t)r * G3 + g * H_]);

        // ---- combined drain: prev half's h-stores + this half's loads
        wait_vm0();
        #pragma unroll
        for (int c = 0; c < 4; ++c)
            *(short8*)&lds_h[half][srow * 520 + scol0 + c*8] = hv[c];
        __syncthreads();

        // ---- post prev half's arrive (its stores are now drained by all threads)
        if (ph > 0 && tid == 0)
            __hip_atomic_fetch_add(cntPrev, 1, __ATOMIC_RELAXED, __HIP_MEMORY_SCOPE_AGENT);

        // ---- recurrent GEMM from LDS, B resident: 16 rows x 48 gate-units slice
        f32x4 acc[3] = {};
        #pragma unroll
        for (int kk = 0; kk < 16; ++kk){
            short8 a = *(const short8*)&lds_h[half][lr * 520 + kk*32 + lk];
            #pragma unroll
            for (int g = 0; g < 3; ++g)
                acc[g] = __builtin_amdgcn_mfma_f32_16x16x32_bf16(a, wreg[g][kk], acc[g], 0, 0, 0);
        }

        // ---- gates + h update; issue stores, DO NOT drain (next phase drains)
        const int t = dir ? (t0b_hi - sl) : (t0f + sl);
        short* hwr = hbb + ((size_t)((rp^1)*2 + dir) * B_) * H_;
        #pragma unroll
        for (int r = 0; r < 4; ++r){
            float gr = acc[0][r] + bh[0] + gv[0][r];
            float gz = acc[1][r] + bh[1] + gv[1][r];
            float gn = acc[2][r] + bh[2];
            float xn = gv[2][r];
            float rg = 1.f / (1.f + __expf(-gr));
            float zg = 1.f / (1.f + __expf(-gz));
            float e2 = __expf(2.f * (xn + rg * gn));
            float ng = 1.f - 2.f / (e2 + 1.f);            // tanh, inf-safe
            float hn = (1.f - zg) * ng + zg * hreg[half][r];
            hreg[half][r] = hn;
            short h16 = f2b(hn);
            const int row = m0 + half*16 + crow + r;
            gstore_sc(hwr + (size_t)row * H_ + u0 + lr, h16);
            xout[((size_t)t * B_ + row) * 1024 + dir*H_ + u0 + lr] = h16;
        }
    }

    // ---- epilogue: drain last phase's stores (half B, sl=SCH-1), post its arrive
    wait_vm0();
    __syncthreads();
    if (tid == 0)
        __hip_atomic_fetch_add(cntB, 1, __ATOMIC_RELAXED, __HIP_MEMORY_SCOPE_AGENT);

    // persist fp32 master across chunk launches
    #pragma unroll
    for (int hf = 0; hf < 2; ++hf)
        #pragma unroll
        for (int r = 0; r < 4; ++r)
            hfm[((size_t)dir*B_ + m0 + hf*16 + crow + r)*H_ + u0 + lr] = hreg[hf][r];
}

// ---------------- final FC + sigmoid ----------------
__global__ void fc_kernel(const short* __restrict__ h, const float* __restrict__ w,
                          const float* __restrict__ b, float* __restrict__ out){
    int wid = threadIdx.x >> 6, lane = threadIdx.x & 63;
    int tb = blockIdx.x * 4 + wid;
    const short* hp = h + (size_t)tb * 1024 + lane * 16;
    float s = 0.f;
    #pragma unroll
    for (int c = 0; c < 2; ++c){
        short8 v = *(const short8*)(hp + c * 8);
        #pragma unroll
        for (int e = 0; e < 8; ++e) s += b2f(v[e]) * w[lane * 16 + c * 8 + e];
    }
    #pragma unroll
    for (int o = 32; o; o >>= 1) s += __shfl_down(s, o);
    if (lane == 0) out[tb] = 1.f / (1.f + __expf(-(s + b[0])));
}

extern "C" void kernel_launch(void* const* d_in, const int* in_sizes, int n_in,
                              void* d_out, int out_size, void* d_ws, size_t ws_size,
                              hipStream_t stream){
    const float* input_seq = (const float*)d_in[0];
    const float* W_ih0 = (const float*)d_in[1];
    const float* W_hh0 = (const float*)d_in[2];
    const float* b_ih0 = (const float*)d_in[3];
    const float* b_hh0 = (const float*)d_in[4];
    const float* W_ih  = (const float*)d_in[5];
    const float* W_hh  = (const float*)d_in[6];
    const float* b_ih  = (const float*)d_in[7];
    const float* b_hh  = (const float*)d_in[8];
    const float* fc_w  = (const float*)d_in[9];
    const float* fc_b  = (const float*)d_in[10];
    (void)in_sizes; (void)n_in; (void)out_size; (void)ws_size;

    char* ws = (char*)d_ws;
    size_t off = 0;
    auto alloc = [&](size_t bytes) -> char* {
        char* p = ws + off; off += (bytes + 255) & ~(size_t)255; return p;
    };
    short* actA = (short*)alloc((size_t)T_*B_*1024 * 2);          // 67.1 MB
    short* actB = (short*)alloc((size_t)T_*B_*1024 * 2);          // 67.1 MB
    short* gxc  = (short*)alloc((size_t)2*SCH*B_*G3 * 2);         // 25.2 MB
    short* wihl = (short*)alloc((size_t)2*G3*1024 * 2);           // 6.3 MB
    short* whhl = (short*)alloc((size_t)2*G3*H_ * 2);             // 3.1 MB
    float* hfm  = (float*)alloc((size_t)2*B_*H_ * 4);             // 0.5 MB
    short* hbb  = (short*)alloc((size_t)2*2*B_*H_ * 2);           // 0.5 MB
    int*   bar  = (int*)alloc(4096);

    auto cvt = [&](const float* s, short* d, size_t n){
        int blocks = (int)((n/4 + 255) / 256); if (blocks > 4096) blocks = 4096;
        hipLaunchKernelGGL(cvt_f32_to_bf16, dim3(blocks), dim3(256), 0, stream, s, d, (int)n);
    };

    // layer-0 input as [T*B][128] bf16 in actB's head
    cvt(input_seq, actB, (size_t)T_*B_*128);

    for (int l = 0; l < 5; ++l){
        const int K = l ? 1024 : 128;
        cvt(l ? W_ih + (size_t)(l-1)*2*G3*1024 : W_ih0, wihl, (size_t)2*G3*K);
        cvt(l ? W_hh + (size_t)(l-1)*2*G3*H_   : W_hh0, whhl, (size_t)2*G3*H_);
        const short* IN  = (l & 1) ? actA : actB;
        short*       OUT = (l & 1) ? actB : actA;
        const float* bi = l ? b_ih + (size_t)(l-1)*2*G3 : b_ih0;
        const float* bh = l ? b_hh + (size_t)(l-1)*2*G3 : b_hh0;

        hipMemsetAsync(hbb, 0, (size_t)2*2*B_*H_*2, stream);   // h(t=0)=0, both parities
        hipMemsetAsync(bar, 0, 4096, stream);                  // arrival counters

        for (int q = 0; q < NCH; ++q){
            const int t0f    = SCH * q;
            const int t0b_hi = T_ - 1 - SCH * q;
            const int t0b_lo = t0b_hi - SCH + 1;
            hipLaunchKernelGGL(gx_gemm, dim3(SCH*B_/128, G3/128, 2), dim3(256), 0, stream,
                               IN, wihl, bi, gxc, K, t0f, t0b_lo);
            hipLaunchKernelGGL(rec_kernel, dim3(RWG, 2), dim3(256), 0, stream,
                               gxc, whhl, bh, OUT, hfm, hbb, bar, t0f, t0b_hi, q == 0, q*SCH);
        }
    }
    // layer 4 wrote actA
    hipLaunchKernelGGL(fc_kernel, dim3((T_*B_)/4), dim3(256), 0, stream,
                       actA, fc_w, fc_b, (float*)d_out);
}